// Round 1
// baseline (1411.453 us; speedup 1.0000x reference)
//
#include <hip/hip_runtime.h>
#include <stdint.h>

#define NCOLS 24576
#define BLOCK 256
#define CAP   2048
// sortable key of 2.0f: 0x40000000 | 0x80000000
#define T0KEY 0xC0000000u

// monotone bijection: float -> uint32, larger float => larger key
__device__ __forceinline__ uint32_t f2k(float f) {
    uint32_t u = __float_as_uint(f);
    return (u & 0x80000000u) ? ~u : (u | 0x80000000u);
}
__device__ __forceinline__ float k2f(uint32_t k) {
    uint32_t u = (k & 0x80000000u) ? (k ^ 0x80000000u) : ~k;
    return __uint_as_float(u);
}

__global__ __launch_bounds__(BLOCK, 4)
void topk_filter_kernel(const float* __restrict__ in, const int* __restrict__ kp,
                        float* __restrict__ out, int nrows) {
    __shared__ uint64_t cand[CAP];   // (key << 32) | (0xFFFFFFFF - col)
    __shared__ int hist[256];
    __shared__ int s_cnt;
    __shared__ int s_bin, s_rem;

    const int row = blockIdx.x;
    if (row >= nrows) return;
    const int tid  = threadIdx.x;
    const int lane = tid & 63;
    const int k    = *kp;

    const float4* inr  = (const float4*)(in  + (size_t)row * NCOLS);
    float4*       outr = (float4*)(out + (size_t)row * NCOLS);
    float*        outrow = out + (size_t)row * NCOLS;
    const float*  inrow  = in  + (size_t)row * NCOLS;

    if (tid == 0) s_cnt = 0;
    __syncthreads();

    // ---- pass 1: read row once, zero output, collect candidates >= 2.0 ----
    const float4 z4 = make_float4(0.f, 0.f, 0.f, 0.f);
    #pragma unroll 4
    for (int i = 0; i < NCOLS / (BLOCK * 4); ++i) {
        int v4 = i * BLOCK + tid;
        float4 v = inr[v4];
        outr[v4] = z4;
        uint32_t keys[4] = {f2k(v.x), f2k(v.y), f2k(v.z), f2k(v.w)};
        #pragma unroll
        for (int j = 0; j < 4; ++j) {
            bool pred = keys[j] >= T0KEY;
            unsigned long long m = __ballot(pred);
            if (m) {  // wave-uniform
                int cnt = __popcll(m);
                int leader = __ffsll(m) - 1;
                int pos = 0;
                if (lane == leader) pos = atomicAdd(&s_cnt, cnt);
                pos = __shfl(pos, leader);
                if (pred) {
                    int my = pos + __popcll(m & ((1ull << lane) - 1ull));
                    if (my < CAP) {
                        uint32_t c = (uint32_t)(v4 * 4 + j);
                        cand[my] = ((uint64_t)keys[j] << 32) | (0xFFFFFFFFu - c);
                    }
                }
            }
        }
    }
    __syncthreads();
    const int n_total = s_cnt;
    const bool fast = (n_total <= CAP) && (n_total >= k) && (k > 0);

    if (fast) {
        const int n = n_total;
        // ---- exact radix select (8-bit digits) over candidate keys ----
        uint32_t prefix = 0; int rem = k;
        for (int shift = 24; shift >= 0; shift -= 8) {
            for (int b = tid; b < 256; b += BLOCK) hist[b] = 0;
            __syncthreads();
            for (int i = tid; i < n; i += BLOCK) {
                uint32_t key = (uint32_t)(cand[i] >> 32);
                uint32_t hi = (uint32_t)shift + 8u;
                bool match = (hi >= 32u) || ((key >> hi) == (prefix >> hi));
                if (match) atomicAdd(&hist[(key >> shift) & 0xFF], 1);
            }
            __syncthreads();
            if (tid == 0) {
                int cum = 0, b = 255;
                for (; b > 0; --b) { cum += hist[b]; if (cum >= rem) break; }
                if (cum < rem) cum += hist[0]; // b==0 catch-all
                s_bin = b; s_rem = rem - (cum - hist[b]);
            }
            __syncthreads();
            prefix |= ((uint32_t)s_bin) << shift;
            rem = s_rem;
            __syncthreads();
        }
        const uint32_t T = prefix;
        const int r = rem;  // # of key==T entries to keep (lowest col first)

        // ---- scatter the exactly-k winners ----
        for (int i = tid; i < n; i += BLOCK) {
            uint64_t p = cand[i];
            uint32_t key = (uint32_t)(p >> 32);
            bool keep = false;
            if (key > T) keep = true;
            else if (key == T) {
                int rank = 0;  // ties with smaller col have larger packed value
                for (int j = 0; j < n; ++j) {
                    uint64_t q = cand[j];
                    if ((uint32_t)(q >> 32) == T && q > p) rank++;
                }
                keep = (rank < r);
            }
            if (keep) {
                uint32_t c = 0xFFFFFFFFu - (uint32_t)p;
                outrow[c] = k2f(key);
            }
        }
    } else {
        // ---- fallback (never taken for N(0,1) data): exact radix select over
        // the full row from global, then ordered tie-rank pass. Correctness only.
        int kk = k;
        if (kk <= 0) return;              // out already zeroed
        if (kk > NCOLS) kk = NCOLS;
        uint32_t prefix = 0; int rem = kk;
        for (int shift = 24; shift >= 0; shift -= 8) {
            for (int b = tid; b < 256; b += BLOCK) hist[b] = 0;
            __syncthreads();
            for (int i = tid; i < NCOLS; i += BLOCK) {
                uint32_t key = f2k(inrow[i]);
                uint32_t hi = (uint32_t)shift + 8u;
                bool match = (hi >= 32u) || ((key >> hi) == (prefix >> hi));
                if (match) atomicAdd(&hist[(key >> shift) & 0xFF], 1);
            }
            __syncthreads();
            if (tid == 0) {
                int cum = 0, b = 255;
                for (; b > 0; --b) { cum += hist[b]; if (cum >= rem) break; }
                if (cum < rem) cum += hist[0];
                s_bin = b; s_rem = rem - (cum - hist[b]);
            }
            __syncthreads();
            prefix |= ((uint32_t)s_bin) << shift;
            rem = s_rem;
            __syncthreads();
        }
        const uint32_t T = prefix;
        const int r = rem;
        // ordered (index-ascending) pass by wave 0 for stable tie-break
        if (tid < 64) {
            int running = 0;
            for (int base = 0; base < NCOLS; base += 64) {
                int c = base + tid;
                float x = inrow[c];
                uint32_t key = f2k(x);
                bool eq = (key == T);
                unsigned long long m = __ballot(eq);
                if (key > T) outrow[c] = x;
                else if (eq) {
                    int rank = running + __popcll(m & ((1ull << tid) - 1ull));
                    if (rank < r) outrow[c] = x;
                }
                running += __popcll(m);
            }
        }
    }
}

extern "C" void kernel_launch(void* const* d_in, const int* in_sizes, int n_in,
                              void* d_out, int out_size, void* d_ws, size_t ws_size,
                              hipStream_t stream) {
    const float* x  = (const float*)d_in[0];
    const int*   kp = (const int*)d_in[1];
    float*       o  = (float*)d_out;
    const int nrows = in_sizes[0] / NCOLS;
    topk_filter_kernel<<<nrows, BLOCK, 0, stream>>>(x, kp, o, nrows);
}

// Round 2
// 1318.103 us; speedup vs baseline: 1.0708x; 1.0708x over previous
//
#include <hip/hip_runtime.h>
#include <stdint.h>

#define NCOLS 24576
#define BLOCK 256
#define CAP   2048
// sortable key of 2.0f: prefilter threshold. P(x>=2.0) ~ 2.3% -> E[cand] ~ 560/row,
// P(cand > 2048) astronomically small; exact fallback below covers it anyway.
#define T0KEY 0xC0000000u

// monotone bijection: float -> uint32, larger float => larger key
__device__ __forceinline__ uint32_t f2k(float f) {
    uint32_t u = __float_as_uint(f);
    return (u & 0x80000000u) ? ~u : (u | 0x80000000u);
}
__device__ __forceinline__ float k2f(uint32_t k) {
    uint32_t u = (k & 0x80000000u) ? (k ^ 0x80000000u) : ~k;
    return __uint_as_float(u);
}

__global__ __launch_bounds__(BLOCK, 4)
void topk_filter_kernel(const float* __restrict__ in, const int* __restrict__ kp,
                        float* __restrict__ out, int nrows) {
    __shared__ uint64_t cand[CAP];   // (key << 32) | (0xFFFFFFFF - col)
    __shared__ int hist[256];
    __shared__ int s_cnt;
    __shared__ int s_bin, s_rem;

    const int row = blockIdx.x;
    if (row >= nrows) return;
    const int tid = threadIdx.x;
    const int k   = *kp;

    const float4* inr  = (const float4*)(in  + (size_t)row * NCOLS);
    float4*       outr = (float4*)(out + (size_t)row * NCOLS);
    float*        outrow = out + (size_t)row * NCOLS;
    const float*  inrow  = in  + (size_t)row * NCOLS;

    if (tid == 0) s_cnt = 0;
    __syncthreads();

    // ---- pass 1: read row once, zero output, collect candidates >= 2.0 ----
    // 24576/4 = 6144 float4 / 256 threads = 24 iters = 3 macro-iters of 8.
    // 8 loads issued back-to-back per wave -> ~8KB/CU in flight for latency hiding.
    const float4 z4 = make_float4(0.f, 0.f, 0.f, 0.f);
    for (int m = 0; m < 3; ++m) {
        float4 v[8];
        #pragma unroll
        for (int j = 0; j < 8; ++j) v[j] = inr[(m * 8 + j) * BLOCK + tid];
        #pragma unroll
        for (int j = 0; j < 8; ++j) outr[(m * 8 + j) * BLOCK + tid] = z4;
        #pragma unroll
        for (int j = 0; j < 8; ++j) {
            uint32_t k0 = f2k(v[j].x), k1 = f2k(v[j].y), k2 = f2k(v[j].z), k3 = f2k(v[j].w);
            int c = (k0 >= T0KEY) + (k1 >= T0KEY) + (k2 >= T0KEY) + (k3 >= T0KEY);
            if (c) {  // ~8.8% of lanes
                int pos = atomicAdd(&s_cnt, c);
                uint32_t base = (uint32_t)(((m * 8 + j) * BLOCK + tid) * 4);
                if (k0 >= T0KEY) { if (pos < CAP) cand[pos] = ((uint64_t)k0 << 32) | (0xFFFFFFFFu - base);       pos++; }
                if (k1 >= T0KEY) { if (pos < CAP) cand[pos] = ((uint64_t)k1 << 32) | (0xFFFFFFFFu - (base + 1)); pos++; }
                if (k2 >= T0KEY) { if (pos < CAP) cand[pos] = ((uint64_t)k2 << 32) | (0xFFFFFFFFu - (base + 2)); pos++; }
                if (k3 >= T0KEY) { if (pos < CAP) cand[pos] = ((uint64_t)k3 << 32) | (0xFFFFFFFFu - (base + 3)); pos++; }
            }
        }
    }
    __syncthreads();
    const int n_total = s_cnt;
    const bool fast = (n_total <= CAP) && (n_total >= k) && (k > 0);

    if (fast) {
        const int n = n_total;
        // ---- exact radix select (8-bit digits), wave0-parallel bin pick ----
        uint32_t prefix = 0; int rem = k;
        for (int shift = 24; shift >= 0; shift -= 8) {
            hist[tid] = 0;                 // BLOCK == 256
            __syncthreads();
            const uint32_t hi = (uint32_t)shift + 8u;
            for (int i = tid; i < n; i += BLOCK) {
                uint32_t key = (uint32_t)(cand[i] >> 32);
                bool match = (hi >= 32u) || ((key >> hi) == (prefix >> hi));
                if (match) atomicAdd(&hist[(key >> shift) & 0xFF], 1);
            }
            __syncthreads();
            if (tid < 64) {
                // 4 bins/lane; suffix sums with zero barriers and no serial chains
                int h0 = hist[tid * 4], h1 = hist[tid * 4 + 1],
                    h2 = hist[tid * 4 + 2], h3 = hist[tid * 4 + 3];
                int tot = h0 + h1 + h2 + h3;
                int t = tot;
                #pragma unroll
                for (int off = 1; off < 64; off <<= 1) {
                    int u = __shfl_down(t, off);
                    if (tid + off < 64) t += u;
                }
                int above = t - tot;       // sum over lanes > me
                int S3 = h3 + above;
                int S2 = h2 + S3;
                int S1 = h1 + S2;
                int S0 = h0 + S1;
                // unique bin b with S(b) >= rem && S(b)-h(b) < rem
                if (S0 >= rem && S0 - h0 < rem) { s_bin = tid * 4 + 0; s_rem = rem - (S0 - h0); }
                if (S1 >= rem && S1 - h1 < rem) { s_bin = tid * 4 + 1; s_rem = rem - (S1 - h1); }
                if (S2 >= rem && S2 - h2 < rem) { s_bin = tid * 4 + 2; s_rem = rem - (S2 - h2); }
                if (S3 >= rem && S3 - h3 < rem) { s_bin = tid * 4 + 3; s_rem = rem - (S3 - h3); }
            }
            __syncthreads();
            prefix |= ((uint32_t)s_bin) << shift;
            rem = s_rem;
            __syncthreads();               // protect s_bin/s_rem vs next pass
        }
        const uint32_t T = prefix;
        const int r = rem;   // # of key==T entries to keep (lowest col first)

        // ---- scatter the exactly-k winners ----
        for (int i = tid; i < n; i += BLOCK) {
            uint64_t p = cand[i];
            uint32_t key = (uint32_t)(p >> 32);
            bool keep = false;
            if (key > T) keep = true;
            else if (key == T) {
                int rank = 0;   // ties with smaller col have larger packed value
                for (int j = 0; j < n; ++j) {
                    uint64_t q = cand[j];
                    if ((uint32_t)(q >> 32) == T && q > p) rank++;
                }
                keep = (rank < r);
            }
            if (keep) {
                uint32_t c = 0xFFFFFFFFu - (uint32_t)p;
                outrow[c] = k2f(key);
            }
        }
    } else {
        // ---- fallback (never taken for N(0,1) data): exact radix select over
        // the full row from global, then ordered tie-rank pass. Correctness only.
        int kk = k;
        if (kk <= 0) return;               // out already zeroed
        if (kk > NCOLS) kk = NCOLS;
        uint32_t prefix = 0; int rem = kk;
        for (int shift = 24; shift >= 0; shift -= 8) {
            hist[tid] = 0;
            __syncthreads();
            const uint32_t hi = (uint32_t)shift + 8u;
            for (int i = tid; i < NCOLS; i += BLOCK) {
                uint32_t key = f2k(inrow[i]);
                bool match = (hi >= 32u) || ((key >> hi) == (prefix >> hi));
                if (match) atomicAdd(&hist[(key >> shift) & 0xFF], 1);
            }
            __syncthreads();
            if (tid == 0) {
                int cum = 0, b = 255;
                for (; b > 0; --b) { cum += hist[b]; if (cum >= rem) break; }
                if (cum < rem) cum += hist[0];
                s_bin = b; s_rem = rem - (cum - hist[b]);
            }
            __syncthreads();
            prefix |= ((uint32_t)s_bin) << shift;
            rem = s_rem;
            __syncthreads();
        }
        const uint32_t T = prefix;
        const int r = rem;
        // ordered (index-ascending) pass by wave 0 for stable tie-break
        if (tid < 64) {
            int running = 0;
            for (int base = 0; base < NCOLS; base += 64) {
                int c = base + tid;
                float x = inrow[c];
                uint32_t key = f2k(x);
                bool eq = (key == T);
                unsigned long long mm = __ballot(eq);
                if (key > T) outrow[c] = x;
                else if (eq) {
                    int rank = running + __popcll(mm & ((1ull << tid) - 1ull));
                    if (rank < r) outrow[c] = x;
                }
                running += __popcll(mm);
            }
        }
    }
}

extern "C" void kernel_launch(void* const* d_in, const int* in_sizes, int n_in,
                              void* d_out, int out_size, void* d_ws, size_t ws_size,
                              hipStream_t stream) {
    const float* x  = (const float*)d_in[0];
    const int*   kp = (const int*)d_in[1];
    float*       o  = (float*)d_out;
    const int nrows = in_sizes[0] / NCOLS;
    topk_filter_kernel<<<nrows, BLOCK, 0, stream>>>(x, kp, o, nrows);
}